// Round 5
// baseline (464.899 us; speedup 1.0000x reference)
//
#include <hip/hip_runtime.h>

#define TW 32
#define TH 32
#define SH 42              // TH + 10 halo rows
#define HPITCH 36          // h-filtered pitch (mult of 4; 36 mod 32 = 4 bank shift)
#define BLOCK 256
#define IMG_W 768
#define IMG_H 768
#define IMG_B 32
#define GX_ (IMG_W / TW)
#define GY_ (IMG_H / TH)
#define NBLOCKS (GX_ * GY_ * IMG_B)   // 18432

// Gaussian window sigma=1.5, ws=11, normalized (f64-computed, f32-cast).
#define W0 0.00102838f
#define W1 0.00759876f
#define W2 0.03600077f
#define W3 0.10936069f
#define W4 0.21300554f
#define W5 0.26601173f

__device__ __forceinline__ void hconv14(const float x[14], float* dst)
{
    constexpr float GW[11] = {W0, W1, W2, W3, W4, W5, W4, W3, W2, W1, W0};
    float a0 = 0.f, a1 = 0.f, a2 = 0.f, a3 = 0.f;
    #pragma unroll
    for (int t = 0; t < 11; ++t) {
        const float w = GW[t];
        a0 += w * x[t];     a1 += w * x[t + 1];
        a2 += w * x[t + 2]; a3 += w * x[t + 3];
    }
    *(float4*)dst = make_float4(a0, a1, a2, a3);
}

__global__ __launch_bounds__(BLOCK, 8) void ssim_tile_kernel(
    const float* __restrict__ pred, const float* __restrict__ yin,
    float* __restrict__ partial)
{
    constexpr float GW[11] = {W0, W1, W2, W3, W4, W5, W4, W3, W2, W1, W0};

    // Only 3 channel planes live at once -> 18.1 KB -> 8 blocks/CU.
    __shared__ __align__(16) float Hb[3][SH][HPITCH];
    __shared__ float wsum[BLOCK / 64];

    const int tid = threadIdx.x;
    const int x0 = blockIdx.x * TW;
    const int y0 = blockIdx.y * TH;
    const size_t base = (size_t)blockIdx.z * (size_t)(IMG_H * IMG_W);
    const float* pb = pred + base;
    const float* yb = yin + base;

    const bool interior = (x0 >= 8) && (x0 + TW + 8 <= IMG_W) &&
                          (y0 >= 5) && (y0 + TH + 5 <= IMG_H);

    const int vc  = tid & 31;
    const int vr0 = (tid >> 5) << 2;

    // ---------------- Phase A: mu channels (p, q) ----------------
    for (int it = tid; it < SH * 8; it += BLOCK) {
        const int hr = it >> 3;
        const int c0 = (it & 7) << 2;
        const int gy = y0 + hr - 5;
        float p[14], q[14];

        if (interior) {
            const float* rp = pb + (size_t)gy * IMG_W + (x0 + c0 - 8);
            const float* rq = yb + (size_t)gy * IMG_W + (x0 + c0 - 8);
            p[0] = rp[3];
            *(float4*)(p + 1) = *(const float4*)(rp + 4);
            *(float4*)(p + 5) = *(const float4*)(rp + 8);
            *(float4*)(p + 9) = *(const float4*)(rp + 12);
            p[13] = rp[16];
            q[0] = rq[3];
            *(float4*)(q + 1) = *(const float4*)(rq + 4);
            *(float4*)(q + 5) = *(const float4*)(rq + 8);
            *(float4*)(q + 9) = *(const float4*)(rq + 12);
            q[13] = rq[16];
        } else {
            if (gy >= 0 && gy < IMG_H) {
                const float* rowp = pb + (size_t)gy * IMG_W;
                const float* rowq = yb + (size_t)gy * IMG_W;
                #pragma unroll
                for (int k = 0; k < 14; ++k) {
                    const int gx = x0 + c0 - 5 + k;
                    const bool in = (gx >= 0) && (gx < IMG_W);
                    p[k] = in ? rowp[gx] : 0.f;
                    q[k] = in ? rowq[gx] : 0.f;
                }
            } else {
                #pragma unroll
                for (int k = 0; k < 14; ++k) { p[k] = 0.f; q[k] = 0.f; }
            }
        }
        hconv14(p, &Hb[0][hr][c0]);
        hconv14(q, &Hb[1][hr][c0]);
    }
    __syncthreads();

    float mu1v[4], mu2v[4];
    {
        float v[14];
        const float* hb0 = &Hb[0][vr0][vc];
        #pragma unroll
        for (int j = 0; j < 14; ++j) v[j] = hb0[j * HPITCH];
        #pragma unroll
        for (int o = 0; o < 4; ++o) {
            float a = 0.f;
            #pragma unroll
            for (int t = 0; t < 11; ++t) a += GW[t] * v[o + t];
            mu1v[o] = a;
        }
        const float* hb1 = &Hb[1][vr0][vc];
        #pragma unroll
        for (int j = 0; j < 14; ++j) v[j] = hb1[j * HPITCH];
        #pragma unroll
        for (int o = 0; o < 4; ++o) {
            float a = 0.f;
            #pragma unroll
            for (int t = 0; t < 11; ++t) a += GW[t] * v[o + t];
            mu2v[o] = a;
        }
    }
    __syncthreads();   // Hb about to be overwritten

    // ---------------- Phase B: product channels (pp, qq, pq) ----------------
    for (int it = tid; it < SH * 8; it += BLOCK) {
        const int hr = it >> 3;
        const int c0 = (it & 7) << 2;
        const int gy = y0 + hr - 5;
        float p[14], q[14];

        if (interior) {
            const float* rp = pb + (size_t)gy * IMG_W + (x0 + c0 - 8);
            const float* rq = yb + (size_t)gy * IMG_W + (x0 + c0 - 8);
            p[0] = rp[3];
            *(float4*)(p + 1) = *(const float4*)(rp + 4);
            *(float4*)(p + 5) = *(const float4*)(rp + 8);
            *(float4*)(p + 9) = *(const float4*)(rp + 12);
            p[13] = rp[16];
            q[0] = rq[3];
            *(float4*)(q + 1) = *(const float4*)(rq + 4);
            *(float4*)(q + 5) = *(const float4*)(rq + 8);
            *(float4*)(q + 9) = *(const float4*)(rq + 12);
            q[13] = rq[16];
        } else {
            if (gy >= 0 && gy < IMG_H) {
                const float* rowp = pb + (size_t)gy * IMG_W;
                const float* rowq = yb + (size_t)gy * IMG_W;
                #pragma unroll
                for (int k = 0; k < 14; ++k) {
                    const int gx = x0 + c0 - 5 + k;
                    const bool in = (gx >= 0) && (gx < IMG_W);
                    p[k] = in ? rowp[gx] : 0.f;
                    q[k] = in ? rowq[gx] : 0.f;
                }
            } else {
                #pragma unroll
                for (int k = 0; k < 14; ++k) { p[k] = 0.f; q[k] = 0.f; }
            }
        }
        float t14[14];
        #pragma unroll
        for (int k = 0; k < 14; ++k) t14[k] = p[k] * p[k];
        hconv14(t14, &Hb[0][hr][c0]);
        #pragma unroll
        for (int k = 0; k < 14; ++k) t14[k] = q[k] * q[k];
        hconv14(t14, &Hb[1][hr][c0]);
        #pragma unroll
        for (int k = 0; k < 14; ++k) t14[k] = p[k] * q[k];
        hconv14(t14, &Hb[2][hr][c0]);
    }
    __syncthreads();

    // ---------------- vertical pass B + SSIM epilogue ----------------
    float m11v[4], m22v[4], m12v[4];
    {
        float v[14];
        #pragma unroll
        for (int ch = 0; ch < 3; ++ch) {
            const float* hb = &Hb[ch][vr0][vc];
            #pragma unroll
            for (int j = 0; j < 14; ++j) v[j] = hb[j * HPITCH];
            #pragma unroll
            for (int o = 0; o < 4; ++o) {
                float a = 0.f;
                #pragma unroll
                for (int t = 0; t < 11; ++t) a += GW[t] * v[o + t];
                if (ch == 0) m11v[o] = a;
                else if (ch == 1) m22v[o] = a;
                else m12v[o] = a;
            }
        }
    }

    const float C1f = 1e-4f;
    const float C2f = 9e-4f;
    float lsum = 0.f;
    #pragma unroll
    for (int o = 0; o < 4; ++o) {
        float mu1 = mu1v[o], mu2 = mu2v[o];
        float mu1s = mu1 * mu1;
        float mu2s = mu2 * mu2;
        float mu12 = mu1 * mu2;
        float s1  = m11v[o] - mu1s;
        float s2  = m22v[o] - mu2s;
        float s12 = m12v[o] - mu12;
        float num = (2.f * mu12 + C1f) * (2.f * s12 + C2f) * (s12 + 0.5f * C2f);
        float den = (mu1s + mu2s + C1f) * (s1 + s2 + C2f) *
                    (__builtin_amdgcn_sqrtf(s1 * s2) + 0.5f * C2f);
        lsum += num * __builtin_amdgcn_rcpf(den);
    }

    // ---- block reduction, plain partial store ----
    #pragma unroll
    for (int off = 32; off > 0; off >>= 1)
        lsum += __shfl_xor(lsum, off);
    const int wid  = tid >> 6;
    const int lane = tid & 63;
    if (lane == 0) wsum[wid] = lsum;
    __syncthreads();
    if (tid == 0) {
        const int bid = (blockIdx.z * GY_ + blockIdx.y) * GX_ + blockIdx.x;
        partial[bid] = wsum[0] + wsum[1] + wsum[2] + wsum[3];
    }
}

// ---------------------------------------------------------------------------
// Deterministic final reduction in double (fixed assignment + order).
// ---------------------------------------------------------------------------
__global__ __launch_bounds__(1024) void ssim_reduce_kernel(
    const float* __restrict__ partial, float* __restrict__ out)
{
    __shared__ double sd[1024];
    double s = 0.0;
    const float4* p4 = (const float4*)partial;      // NBLOCKS % 4 == 0
    for (int i = threadIdx.x; i < NBLOCKS / 4; i += 1024) {
        float4 v = p4[i];
        s += (double)v.x + (double)v.y + (double)v.z + (double)v.w;
    }
    sd[threadIdx.x] = s;
    __syncthreads();
    #pragma unroll
    for (int st = 512; st > 0; st >>= 1) {
        if (threadIdx.x < st) sd[threadIdx.x] += sd[threadIdx.x + st];
        __syncthreads();
    }
    if (threadIdx.x == 0)
        out[0] = (float)(sd[0] * (1.0 / ((double)IMG_B * IMG_H * IMG_W)));
}

extern "C" void kernel_launch(void* const* d_in, const int* in_sizes, int n_in,
                              void* d_out, int out_size, void* d_ws, size_t ws_size,
                              hipStream_t stream)
{
    const float* pred = (const float*)d_in[0];
    const float* yin  = (const float*)d_in[1];
    float* out     = (float*)d_out;
    float* partial = (float*)d_ws;

    dim3 grid(GX_, GY_, IMG_B);   // 24 x 24 x 32
    ssim_tile_kernel<<<grid, BLOCK, 0, stream>>>(pred, yin, partial);
    ssim_reduce_kernel<<<1, 1024, 0, stream>>>(partial, out);
}

// Round 6
// 420.543 us; speedup vs baseline: 1.1055x; 1.1055x over previous
//
#include <hip/hip_runtime.h>

#define TW 32
#define TH 32
#define SH 42              // TH + 10 halo rows
#define HPITCH 36          // h-filtered pitch (mult of 4; 36 mod 32 = 4 bank shift)
#define BLOCK 256
#define IMG_W 768
#define IMG_H 768
#define IMG_B 32
#define GX_ (IMG_W / TW)
#define GY_ (IMG_H / TH)
#define NBLOCKS (GX_ * GY_ * IMG_B)   // 18432

// Gaussian window sigma=1.5, ws=11, normalized (f64-computed, f32-cast).
#define W0 0.00102838f
#define W1 0.00759876f
#define W2 0.03600077f
#define W3 0.10936069f
#define W4 0.21300554f
#define W5 0.26601173f

__device__ __forceinline__ void hconv14(const float x[14], float* dst)
{
    constexpr float GW[11] = {W0, W1, W2, W3, W4, W5, W4, W3, W2, W1, W0};
    float a0 = 0.f, a1 = 0.f, a2 = 0.f, a3 = 0.f;
    #pragma unroll
    for (int t = 0; t < 11; ++t) {
        const float w = GW[t];
        a0 += w * x[t];     a1 += w * x[t + 1];
        a2 += w * x[t + 2]; a3 += w * x[t + 3];
    }
    *(float4*)dst = make_float4(a0, a1, a2, a3);
}

// 7 waves/EU -> 73-VGPR budget (live set ~55-60; 8 waves' 64 cap spilled ~26
// slots/thread in R5 -> 1 GB scratch traffic). LDS 18.4 KB -> 7 blocks/CU.
__global__ __launch_bounds__(BLOCK, 7) void ssim_tile_kernel(
    const float* __restrict__ pred, const float* __restrict__ yin,
    float* __restrict__ partial)
{
    constexpr float GW[11] = {W0, W1, W2, W3, W4, W5, W4, W3, W2, W1, W0};

    // Only 3 channel planes live at once.
    __shared__ __align__(16) float Hb[3][SH][HPITCH];
    __shared__ float wsum[BLOCK / 64];

    const int tid = threadIdx.x;
    const int x0 = blockIdx.x * TW;
    const int y0 = blockIdx.y * TH;
    const size_t base = (size_t)blockIdx.z * (size_t)(IMG_H * IMG_W);
    const float* pb = pred + base;
    const float* yb = yin + base;

    const bool interior = (x0 >= 8) && (x0 + TW + 8 <= IMG_W) &&
                          (y0 >= 5) && (y0 + TH + 5 <= IMG_H);

    const int vc  = tid & 31;
    const int vr0 = (tid >> 5) << 2;

    // ---------------- Phase A: mu channels (p, q) ----------------
    for (int it = tid; it < SH * 8; it += BLOCK) {
        const int hr = it >> 3;
        const int c0 = (it & 7) << 2;
        const int gy = y0 + hr - 5;
        float p[14], q[14];

        if (interior) {
            const float* rp = pb + (size_t)gy * IMG_W + (x0 + c0 - 8);
            const float* rq = yb + (size_t)gy * IMG_W + (x0 + c0 - 8);
            p[0] = rp[3];
            *(float4*)(p + 1) = *(const float4*)(rp + 4);
            *(float4*)(p + 5) = *(const float4*)(rp + 8);
            *(float4*)(p + 9) = *(const float4*)(rp + 12);
            p[13] = rp[16];
            q[0] = rq[3];
            *(float4*)(q + 1) = *(const float4*)(rq + 4);
            *(float4*)(q + 5) = *(const float4*)(rq + 8);
            *(float4*)(q + 9) = *(const float4*)(rq + 12);
            q[13] = rq[16];
        } else {
            if (gy >= 0 && gy < IMG_H) {
                const float* rowp = pb + (size_t)gy * IMG_W;
                const float* rowq = yb + (size_t)gy * IMG_W;
                #pragma unroll
                for (int k = 0; k < 14; ++k) {
                    const int gx = x0 + c0 - 5 + k;
                    const bool in = (gx >= 0) && (gx < IMG_W);
                    p[k] = in ? rowp[gx] : 0.f;
                    q[k] = in ? rowq[gx] : 0.f;
                }
            } else {
                #pragma unroll
                for (int k = 0; k < 14; ++k) { p[k] = 0.f; q[k] = 0.f; }
            }
        }
        hconv14(p, &Hb[0][hr][c0]);
        hconv14(q, &Hb[1][hr][c0]);
    }
    __syncthreads();

    float mu1v[4], mu2v[4];
    {
        float v[14];
        const float* hb0 = &Hb[0][vr0][vc];
        #pragma unroll
        for (int j = 0; j < 14; ++j) v[j] = hb0[j * HPITCH];
        #pragma unroll
        for (int o = 0; o < 4; ++o) {
            float a = 0.f;
            #pragma unroll
            for (int t = 0; t < 11; ++t) a += GW[t] * v[o + t];
            mu1v[o] = a;
        }
        const float* hb1 = &Hb[1][vr0][vc];
        #pragma unroll
        for (int j = 0; j < 14; ++j) v[j] = hb1[j * HPITCH];
        #pragma unroll
        for (int o = 0; o < 4; ++o) {
            float a = 0.f;
            #pragma unroll
            for (int t = 0; t < 11; ++t) a += GW[t] * v[o + t];
            mu2v[o] = a;
        }
    }
    __syncthreads();   // Hb about to be overwritten

    // ---------------- Phase B: product channels (pp, qq, pq) ----------------
    for (int it = tid; it < SH * 8; it += BLOCK) {
        const int hr = it >> 3;
        const int c0 = (it & 7) << 2;
        const int gy = y0 + hr - 5;
        float p[14], q[14];

        if (interior) {
            const float* rp = pb + (size_t)gy * IMG_W + (x0 + c0 - 8);
            const float* rq = yb + (size_t)gy * IMG_W + (x0 + c0 - 8);
            p[0] = rp[3];
            *(float4*)(p + 1) = *(const float4*)(rp + 4);
            *(float4*)(p + 5) = *(const float4*)(rp + 8);
            *(float4*)(p + 9) = *(const float4*)(rp + 12);
            p[13] = rp[16];
            q[0] = rq[3];
            *(float4*)(q + 1) = *(const float4*)(rq + 4);
            *(float4*)(q + 5) = *(const float4*)(rq + 8);
            *(float4*)(q + 9) = *(const float4*)(rq + 12);
            q[13] = rq[16];
        } else {
            if (gy >= 0 && gy < IMG_H) {
                const float* rowp = pb + (size_t)gy * IMG_W;
                const float* rowq = yb + (size_t)gy * IMG_W;
                #pragma unroll
                for (int k = 0; k < 14; ++k) {
                    const int gx = x0 + c0 - 5 + k;
                    const bool in = (gx >= 0) && (gx < IMG_W);
                    p[k] = in ? rowp[gx] : 0.f;
                    q[k] = in ? rowq[gx] : 0.f;
                }
            } else {
                #pragma unroll
                for (int k = 0; k < 14; ++k) { p[k] = 0.f; q[k] = 0.f; }
            }
        }
        float t14[14];
        #pragma unroll
        for (int k = 0; k < 14; ++k) t14[k] = p[k] * p[k];
        hconv14(t14, &Hb[0][hr][c0]);
        #pragma unroll
        for (int k = 0; k < 14; ++k) t14[k] = q[k] * q[k];
        hconv14(t14, &Hb[1][hr][c0]);
        #pragma unroll
        for (int k = 0; k < 14; ++k) t14[k] = p[k] * q[k];
        hconv14(t14, &Hb[2][hr][c0]);
    }
    __syncthreads();

    // ---------------- vertical pass B + SSIM epilogue ----------------
    float m11v[4], m22v[4], m12v[4];
    {
        float v[14];
        #pragma unroll
        for (int ch = 0; ch < 3; ++ch) {
            const float* hb = &Hb[ch][vr0][vc];
            #pragma unroll
            for (int j = 0; j < 14; ++j) v[j] = hb[j * HPITCH];
            #pragma unroll
            for (int o = 0; o < 4; ++o) {
                float a = 0.f;
                #pragma unroll
                for (int t = 0; t < 11; ++t) a += GW[t] * v[o + t];
                if (ch == 0) m11v[o] = a;
                else if (ch == 1) m22v[o] = a;
                else m12v[o] = a;
            }
        }
    }

    const float C1f = 1e-4f;
    const float C2f = 9e-4f;
    float lsum = 0.f;
    #pragma unroll
    for (int o = 0; o < 4; ++o) {
        float mu1 = mu1v[o], mu2 = mu2v[o];
        float mu1s = mu1 * mu1;
        float mu2s = mu2 * mu2;
        float mu12 = mu1 * mu2;
        float s1  = m11v[o] - mu1s;
        float s2  = m22v[o] - mu2s;
        float s12 = m12v[o] - mu12;
        float num = (2.f * mu12 + C1f) * (2.f * s12 + C2f) * (s12 + 0.5f * C2f);
        float den = (mu1s + mu2s + C1f) * (s1 + s2 + C2f) *
                    (__builtin_amdgcn_sqrtf(s1 * s2) + 0.5f * C2f);
        lsum += num * __builtin_amdgcn_rcpf(den);
    }

    // ---- block reduction, plain partial store ----
    #pragma unroll
    for (int off = 32; off > 0; off >>= 1)
        lsum += __shfl_xor(lsum, off);
    const int wid  = tid >> 6;
    const int lane = tid & 63;
    if (lane == 0) wsum[wid] = lsum;
    __syncthreads();
    if (tid == 0) {
        const int bid = (blockIdx.z * GY_ + blockIdx.y) * GX_ + blockIdx.x;
        partial[bid] = wsum[0] + wsum[1] + wsum[2] + wsum[3];
    }
}

// ---------------------------------------------------------------------------
// Deterministic final reduction in double (fixed assignment + order).
// ---------------------------------------------------------------------------
__global__ __launch_bounds__(1024) void ssim_reduce_kernel(
    const float* __restrict__ partial, float* __restrict__ out)
{
    __shared__ double sd[1024];
    double s = 0.0;
    const float4* p4 = (const float4*)partial;      // NBLOCKS % 4 == 0
    for (int i = threadIdx.x; i < NBLOCKS / 4; i += 1024) {
        float4 v = p4[i];
        s += (double)v.x + (double)v.y + (double)v.z + (double)v.w;
    }
    sd[threadIdx.x] = s;
    __syncthreads();
    #pragma unroll
    for (int st = 512; st > 0; st >>= 1) {
        if (threadIdx.x < st) sd[threadIdx.x] += sd[threadIdx.x + st];
        __syncthreads();
    }
    if (threadIdx.x == 0)
        out[0] = (float)(sd[0] * (1.0 / ((double)IMG_B * IMG_H * IMG_W)));
}

extern "C" void kernel_launch(void* const* d_in, const int* in_sizes, int n_in,
                              void* d_out, int out_size, void* d_ws, size_t ws_size,
                              hipStream_t stream)
{
    const float* pred = (const float*)d_in[0];
    const float* yin  = (const float*)d_in[1];
    float* out     = (float*)d_out;
    float* partial = (float*)d_ws;

    dim3 grid(GX_, GY_, IMG_B);   // 24 x 24 x 32
    ssim_tile_kernel<<<grid, BLOCK, 0, stream>>>(pred, yin, partial);
    ssim_reduce_kernel<<<1, 1024, 0, stream>>>(partial, out);
}